// Round 1
// baseline (192.774 us; speedup 1.0000x reference)
//
#include <hip/hip_runtime.h>
#include <cstdint>

// StreamNet K3 S1 halo conv, bf16 MFMA implicit-GEMM.
// R7: occupancy restructure. R6 ran 512 blocks x 4 tiles with a 65KB
// double-buffered LDS pipeline -> 2 blocks/CU, Occupancy 17%, everything
// idle (MfmaUtil 5%, VALUBusy 9%, HBM 30%). R7 runs 2048 blocks x 1 tile,
// single 23.3KB LDS buffer whose low region doubles as the W staging area
// (W is consumed into registers before the X tile overwrites it).
// __launch_bounds__(256,4) -> 4 blocks/CU, 50% occupancy ceiling; cross-
// block TLP replaces the intra-block double buffer. Staged X tile is
// packed to bf16 in registers (24 u32) before the LDS store to keep the
// Bf(72) + staging live set under the 128-VGPR budget.
//
// Padded input Xp[b][c][r][cc], r,cc in [0,258):
//   r < 2           -> bbuf[b][c][r][cc]           (bbuf [B][C][2][258])
//   r>=2, cc < 2    -> rbuf[b][c][r-2][cc]         (rbuf [B][C][256][2])
//   r>=2, cc>=2     -> (cc-2 == 255) ? 0 : x[b][c][r-2][cc-2]

constexpr int B  = 8;
constexpr int C  = 32;
constexpr int P  = 256;
constexpr int KB = 2;
constexpr int TILE = 16;
constexpr int RS = 20;            // LDS row stride (dwords)
constexpr int PL = 364;           // plane stride (dwords); 364%32=12 -> A reads 2-way, free
constexpr int XSZ = 16 * PL;      // 5824 dwords = 23296 B (also covers Ws: 4608 dwords)

typedef short bf16x8 __attribute__((ext_vector_type(8)));
typedef float f32x4  __attribute__((ext_vector_type(4)));
union Frag { uint32_t u[4]; bf16x8 v; };

static __device__ __forceinline__ uint32_t pk_bf16(float lo, float hi) {
    uint32_t a  = __builtin_bit_cast(uint32_t, lo);
    uint32_t b2 = __builtin_bit_cast(uint32_t, hi);
    a  += 0x7FFFu + ((a  >> 16) & 1u);
    b2 += 0x7FFFu + ((b2 >> 16) & 1u);
    return (a >> 16) | (b2 & 0xFFFF0000u);
}

__global__ __launch_bounds__(256, 4) void conv_mfma(
    const float* __restrict__ x,      // [B][C][P][P]
    const float* __restrict__ rbuf,   // [B][C][P][KB]
    const float* __restrict__ bbuf,   // [B][C][KB][P+KB]
    const float* __restrict__ W,      // [C][C][3][3]
    const float* __restrict__ bias,   // [C]
    float* __restrict__ out)          // [B][C][P][P]
{
    const int tid  = threadIdx.x;
    const int lane = tid & 63;
    const int w    = tid >> 6;        // wave 0..3
    const int q    = lane >> 4;
    const int n16  = lane & 15;

    const int blk = blockIdx.x;       // 0..2047
    const int tx = blk & 15, ty = (blk >> 4) & 15, b = blk >> 8;   // b in 0..7
    const int x0 = tx * TILE, y0 = ty * TILE;

    __shared__ uint32_t Xs[XSZ];      // 23296 B; [0,4608) doubles as Ws first

    // ---- W stage into the low region of Xs (consumed into Bf before X store) ----
    #pragma unroll
    for (int k = 0; k < 18; ++k) {
        const int u  = tid + k * 256;
        const int m  = u & 15;
        const int oc = (u >> 4) & 31;
        const int t  = u >> 9;
        const float lo = W[(oc * C + 2 * m) * 9 + t];
        const float hi = W[(oc * C + 2 * m + 1) * 9 + t];
        Xs[t * 512 + oc * 16 + m] = pk_bf16(lo, hi);
    }

    // ---- staging lane geometry ----
    const int irow  = lane >> 2;                 // 0..15
    const int icol4 = (lane & 3) * 4;            // 0,4,8,12
    const bool zc   = (x0 == P - TILE) && ((lane & 3) == 3);  // xc==255 in .w

    // halo cells: generic source resolution (sel: 0=x, 1=rbuf, 2=bbuf)
    const int t_r = lane >= 18 ? 1 : 0;          // top halo patch row
    const int t_c = lane - 18 * t_r;             // top halo patch col 0..17
    int t_sel = 0, t_off = 0; bool t_zero = false;
    {
        const int rg = y0 + t_r, cg = x0 + t_c;
        if (rg < KB)      { t_sel = 2; t_off = rg * (P + KB) + cg; }
        else if (cg < KB) { t_sel = 1; t_off = (rg - KB) * KB + cg; }
        else              { t_sel = 0; t_off = (rg - KB) * P + (cg - KB);
                            t_zero = (cg == P + KB - 1); }
    }
    const int l_r = lane >> 1;                   // 0..15 -> patch row l_r+2
    const int l_c = lane & 1;                    // patch col 0..1
    int l_sel = 0, l_off = 0;
    {
        const int rg = y0 + KB + l_r, cg = x0 + l_c;   // rg >= 2 always
        if (cg < KB) { l_sel = 1; l_off = (rg - KB) * KB + cg; }
        else         { l_sel = 0; l_off = (rg - KB) * P + (cg - KB); }  // never col 255
    }

    // ---- X tile: global loads + in-register bf16 pack (24 u32 live) ----
    const float* xb = x    + (size_t)b * C * P * P;
    const float* rb = rbuf + (size_t)b * C * P * KB;
    const float* bb = bbuf + (size_t)b * C * KB * (P + KB);
    const float* basep[3] = { xb, rb, bb };
    const int    psz[3]   = { P * P, P * KB, KB * (P + KB) };

    uint32_t ipk[4][4], tpk[4], lpk[4];
    #pragma unroll
    for (int k2 = 0; k2 < 4; ++k2) {
        const int m = 4 * k2 + w;                // ic-pair owned by this wave
        const float* pi = xb + (2 * m) * (P * P) + (y0 + irow) * P + x0 + icol4;
        float4 lo = *(const float4*)pi;
        float4 hi = *(const float4*)(pi + P * P);
        if (zc) { lo.w = 0.f; hi.w = 0.f; }
        ipk[k2][0] = pk_bf16(lo.x, hi.x);
        ipk[k2][1] = pk_bf16(lo.y, hi.y);
        ipk[k2][2] = pk_bf16(lo.z, hi.z);
        ipk[k2][3] = pk_bf16(lo.w, hi.w);
        if (lane < 36) {
            const float* pt = basep[t_sel] + (size_t)(2 * m) * psz[t_sel] + t_off;
            tpk[k2] = t_zero ? 0u : pk_bf16(pt[0], pt[psz[t_sel]]);
        }
        if (lane < 32) {
            const float* pl = basep[l_sel] + (size_t)(2 * m) * psz[l_sel] + l_off;
            lpk[k2] = pk_bf16(pl[0], pl[psz[l_sel]]);
        }
    }

    __syncthreads();   // W ds_writes visible to all waves

    // ---- B fragments: registers for the whole kernel ----
    Frag Bf[9][2];
    #pragma unroll
    for (int t = 0; t < 9; ++t)
        #pragma unroll
        for (int oh = 0; oh < 2; ++oh) {
            const uint32_t* src = &Xs[t * 512 + (oh * 16 + n16) * 16 + q * 4];
            Bf[t][oh].u[0] = src[0]; Bf[t][oh].u[1] = src[1];
            Bf[t][oh].u[2] = src[2]; Bf[t][oh].u[3] = src[3];
        }
    const float bv0 = bias[n16];
    const float bv1 = bias[16 + n16];

    __syncthreads();   // all Ws reads done before the X tile overwrites it

    // ---- store packed tile to LDS ----
    #pragma unroll
    for (int k2 = 0; k2 < 4; ++k2) {
        const int m = 4 * k2 + w;
        uint32_t* dst = Xs + m * PL + (irow + KB) * RS + (icol4 + KB);
        dst[0] = ipk[k2][0];
        dst[1] = ipk[k2][1];
        dst[2] = ipk[k2][2];
        dst[3] = ipk[k2][3];
        if (lane < 36) Xs[m * PL + t_r * RS + t_c]        = tpk[k2];
        if (lane < 32) Xs[m * PL + (l_r + KB) * RS + l_c] = lpk[k2];
    }
    __syncthreads();

    // ---- MFMA sweep ----
    f32x4 acc[4][2];
    #pragma unroll
    for (int rr = 0; rr < 4; ++rr)
        #pragma unroll
        for (int oh = 0; oh < 2; ++oh)
            #pragma unroll
            for (int e = 0; e < 4; ++e) acc[rr][oh][e] = 0.f;

    // A-frags deduped: patch row 4w+dr serves all (rr,ky) with rr+ky==dr
    #pragma unroll
    for (int dr = 0; dr < 6; ++dr) {
        Frag A[3];
        const uint32_t* ap = Xs + (4 * q) * PL + (4 * w + dr) * RS + n16;
        #pragma unroll
        for (int kx = 0; kx < 3; ++kx)
            #pragma unroll
            for (int p = 0; p < 4; ++p)
                A[kx].u[p] = ap[p * PL + kx];
        #pragma unroll
        for (int ky = 0; ky < 3; ++ky) {
            const int rr = dr - ky;
            if (rr >= 0 && rr < 4) {
                #pragma unroll
                for (int kx = 0; kx < 3; ++kx) {
                    acc[rr][0] = __builtin_amdgcn_mfma_f32_16x16x32_bf16(
                                     A[kx].v, Bf[ky * 3 + kx][0].v, acc[rr][0], 0, 0, 0);
                    acc[rr][1] = __builtin_amdgcn_mfma_f32_16x16x32_bf16(
                                     A[kx].v, Bf[ky * 3 + kx][1].v, acc[rr][1], 0, 0, 0);
                }
            }
        }
    }

    // ---- epilogue: D[m=px 4q+e][n=oc n16] -> float4 stores ----
    #pragma unroll
    for (int oh = 0; oh < 2; ++oh) {
        const int oc = oh * 16 + n16;
        const float bv = oh ? bv1 : bv0;
        #pragma unroll
        for (int rr = 0; rr < 4; ++rr) {
            float4 v;
            v.x = acc[rr][oh][0] + bv;
            v.y = acc[rr][oh][1] + bv;
            v.z = acc[rr][oh][2] + bv;
            v.w = acc[rr][oh][3] + bv;
            *(float4*)&out[((size_t)(b * C + oc) * P + (y0 + 4 * w + rr)) * P + x0 + 4 * q] = v;
        }
    }
}

extern "C" void kernel_launch(void* const* d_in, const int* in_sizes, int n_in,
                              void* d_out, int out_size, void* d_ws, size_t ws_size,
                              hipStream_t stream) {
    const float* x    = (const float*)d_in[0];
    const float* rbuf = (const float*)d_in[1];
    const float* bbuf = (const float*)d_in[2];
    const float* W    = (const float*)d_in[3];
    const float* bias = (const float*)d_in[4];
    float* out = (float*)d_out;

    conv_mfma<<<2048, 256, 0, stream>>>(x, rbuf, bbuf, W, bias, out);
}

// Round 3
// 167.680 us; speedup vs baseline: 1.1497x; 1.1497x over previous
//
#include <hip/hip_runtime.h>
#include <cstdint>

// StreamNet K3 S1 halo conv, bf16 MFMA implicit-GEMM.
// R8b: R8 with the nontemporal-store type fixed (__builtin_nontemporal_store
// requires a clang ext_vector pointer, not HIP's float4 struct).
// R8 rationale: R6/R7 both saturated at ~2.45 TB/s regardless of occupancy
// (17% vs 34%) -> BW is pattern-limited: 16-wide tiles issue scattered 64B
// read chunks (39% DRAM efficiency). R7 also spilled (VGPR=64 < Bf's 72 ->
// +60MB scratch traffic). R8:
//   * 16x32 tiles: per-lane 32B, per-row 128B contiguous reads; halo
//     overfetch 1.266 -> 1.195x. Grid 1024 (8cx x 16ty x 8b).
//   * MFMA sweep split by column-half ch (A-frags disjoint -> no extra
//     LDS reads; acc stays 32 f32 -> live set ~140 regs, no spill).
//   * Single LDS buffer 41.7KB, W overlaid in Xs low region (consumed
//     into Bf regs before X overwrites it) -> 3 blocks/CU at (256,3).
//   * Register-double-buffered staging: ld(k+1) issued before st(k).
//   * XCD swizzle: XCD i owns batch i -> halo re-reads stay in-XCD L2.
//   * W staged via float4 loads; out stores nontemporal.
//
// Padded input Xp[b][c][r][cc], r,cc in [0,258):
//   r < 2           -> bbuf[b][c][r][cc]           (bbuf [B][C][2][258])
//   r>=2, cc < 2    -> rbuf[b][c][r-2][cc]         (rbuf [B][C][256][2])
//   r>=2, cc>=2     -> (cc-2 == 255) ? 0 : x[b][c][r-2][cc-2]

constexpr int B  = 8;
constexpr int C  = 32;
constexpr int P  = 256;
constexpr int KB = 2;
constexpr int TH = 16;            // tile rows
constexpr int TW = 32;            // tile cols
constexpr int RS = 36;            // LDS row stride (dwords); padded col pc stored at 2+pc
constexpr int PL = 652;           // plane stride (dwords); %32=12 (A reads 2-way free), %4=0
constexpr int XSZ = 16 * PL;      // 10432 dwords = 41728 B (covers W overlay: 4608 dw)

typedef short bf16x8 __attribute__((ext_vector_type(8)));
typedef float f32x4  __attribute__((ext_vector_type(4)));
union Frag { uint32_t u[4]; bf16x8 v; };

static __device__ __forceinline__ uint32_t pk_bf16(float lo, float hi) {
    uint32_t a  = __builtin_bit_cast(uint32_t, lo);
    uint32_t b2 = __builtin_bit_cast(uint32_t, hi);
    a  += 0x7FFFu + ((a  >> 16) & 1u);
    b2 += 0x7FFFu + ((b2 >> 16) & 1u);
    return (a >> 16) | (b2 & 0xFFFF0000u);
}

struct St {                        // one plane-pair's staged data
    float4 a0, a1, c0, c1;         // interior: lo plane 8 cols, hi plane 8 cols
    float  h0l, h0h, h1l, h1h;     // 2 halo cells x (lo, hi)
};

__global__ __launch_bounds__(256, 3) void conv_mfma(
    const float* __restrict__ x,      // [B][C][P][P]
    const float* __restrict__ rbuf,   // [B][C][P][KB]
    const float* __restrict__ bbuf,   // [B][C][KB][P+KB]
    const float* __restrict__ W,      // [C][C][3][3]
    const float* __restrict__ bias,   // [C]
    float* __restrict__ out)          // [B][C][P][P]
{
    const int tid  = threadIdx.x;
    const int lane = tid & 63;
    const int w    = tid >> 6;        // wave 0..3
    const int q    = lane >> 4;
    const int n16  = lane & 15;

    // XCD swizzle: round-robin dispatch (blk%8 = XCD) -> XCD i gets swz
    // range [128i,128(i+1)) = all tiles of batch i (8.4MB x, in-XCD halos)
    const int swz = (blockIdx.x & 7) * 128 + (blockIdx.x >> 3);
    const int cx = swz & 7, ty = (swz >> 3) & 15, b = swz >> 7;
    const int x0 = cx * TW, y0 = ty * TH;

    __shared__ uint32_t Xs[XSZ];      // low 4608 dwords double as Ws first

    // ---- W stage (float4 loads, ds_write_b16 scatter) ----
    {
        const float4* W4 = (const float4*)W;       // 2304 float4
        uint16_t* Wh = (uint16_t*)Xs;
        #pragma unroll
        for (int k = 0; k < 9; ++k) {
            const int idx = tid + k * 256;         // 0..2303
            const float4 v = W4[idx];
            const int f = idx * 4;
            const float vv[4] = { v.x, v.y, v.z, v.w };
            #pragma unroll
            for (int e = 0; e < 4; ++e) {
                const int flat = f + e;            // (oc*32+ic)*9 + t
                const int t    = flat % 9;
                const int rest = flat / 9;
                const int ic   = rest & 31;
                const int oc   = rest >> 5;
                const uint32_t u = __builtin_bit_cast(uint32_t, vv[e]);
                const uint16_t h = (uint16_t)((u + 0x7FFFu + ((u >> 16) & 1u)) >> 16);
                Wh[(t * 512 + oc * 16 + (ic >> 1)) * 2 + (ic & 1)] = h;
            }
        }
    }

    // ---- staging lane geometry ----
    const int srow = lane >> 2;                    // 0..15
    const int scol = (lane & 3) * 8;               // 0,8,16,24 (8 cols/lane)
    const bool zc  = (x0 == P - TW) && ((lane & 3) == 3);   // col 255 lands in a1.w/c1.w

    // halo cells: 100 = top 2x34 (idx 0..67) + left 16x2 (idx 68..99)
    const float* xb = x    + (size_t)b * C * P * P;
    const float* rb = rbuf + (size_t)b * C * P * KB;
    const float* bb = bbuf + (size_t)b * C * KB * (P + KB);
    const float* basep[3] = { xb, rb, bb };
    const int    psz[3]   = { P * P, P * KB, KB * (P + KB) };

    int h_ldso[2], h_ps[2];
    const float* h_bp[2];
    bool h_z[2];
    #pragma unroll
    for (int ci = 0; ci < 2; ++ci) {
        const int c = lane + 64 * ci;
        int prow, pcol;
        if (c < 68) { const int hr = (c >= 34) ? 1 : 0; prow = hr; pcol = c - 34 * hr; }
        else        { const int cc = c - 68; prow = KB + (cc >> 1); pcol = cc & 1; }
        h_ldso[ci] = prow * RS + 2 + pcol;
        const int gr = y0 + prow, gc = x0 + pcol;
        int sel, off; bool z = false;
        if (gr < KB)      { sel = 2; off = gr * (P + KB) + gc; }
        else if (gc < KB) { sel = 1; off = (gr - KB) * KB + gc; }
        else              { sel = 0; off = (gr - KB) * P + (gc - KB); z = (gc == P + KB - 1); }
        h_bp[ci] = basep[sel] + off;
        h_ps[ci] = psz[sel];
        h_z[ci]  = z;
    }
    const bool h1a = lane < 36;                    // cell1 active

    auto ld = [&](int m, St& S) {
        const float* pi = xb + (size_t)(2 * m) * (P * P) + (y0 + srow) * P + x0 + scol;
        S.a0 = *(const float4*)pi;
        S.a1 = *(const float4*)(pi + 4);
        S.c0 = *(const float4*)(pi + P * P);
        S.c1 = *(const float4*)(pi + P * P + 4);
        const float* p0 = h_bp[0] + (size_t)(2 * m) * h_ps[0];
        S.h0l = h_z[0] ? 0.f : p0[0];
        S.h0h = h_z[0] ? 0.f : p0[h_ps[0]];
        if (h1a) {
            const float* p1 = h_bp[1] + (size_t)(2 * m) * h_ps[1];
            S.h1l = h_z[1] ? 0.f : p1[0];
            S.h1h = h_z[1] ? 0.f : p1[h_ps[1]];
        }
    };

    auto st = [&](int m, St& S) {
        float4 a1 = S.a1, c1 = S.c1;
        if (zc) { a1.w = 0.f; c1.w = 0.f; }
        uint4 u0, u1;
        u0.x = pk_bf16(S.a0.x, S.c0.x); u0.y = pk_bf16(S.a0.y, S.c0.y);
        u0.z = pk_bf16(S.a0.z, S.c0.z); u0.w = pk_bf16(S.a0.w, S.c0.w);
        u1.x = pk_bf16(a1.x,  c1.x);  u1.y = pk_bf16(a1.y,  c1.y);
        u1.z = pk_bf16(a1.z,  c1.z);  u1.w = pk_bf16(a1.w,  c1.w);
        uint32_t* base = Xs + m * PL + (srow + KB) * RS + 4 + scol;  // 16B aligned
        *(uint4*)base       = u0;
        *(uint4*)(base + 4) = u1;
        Xs[m * PL + h_ldso[0]] = pk_bf16(S.h0l, S.h0h);
        if (h1a) Xs[m * PL + h_ldso[1]] = pk_bf16(S.h1l, S.h1h);
    };

    // ---- prologue: issue first staging loads before W sync ----
    St S0, S1;
    ld(w, S0);                    // m = w (k2=0)

    __syncthreads();              // W ds_writes visible

    // ---- B fragments: ds_read_b128 each ----
    Frag Bf[9][2];
    #pragma unroll
    for (int t = 0; t < 9; ++t)
        #pragma unroll
        for (int oh = 0; oh < 2; ++oh)
            *(uint4*)Bf[t][oh].u = *(const uint4*)&Xs[t * 512 + (oh * 16 + n16) * 16 + q * 4];
    const float bv0 = bias[n16];
    const float bv1 = bias[16 + n16];

    __syncthreads();              // all Ws reads done; Xs reusable for X tile

    // ---- staging: reg-double-buffered (ld k+1 issued before st k) ----
    ld(4 + w, S1);   st(w, S0);
    ld(8 + w, S0);   st(4 + w, S1);
    ld(12 + w, S1);  st(8 + w, S0);
    st(12 + w, S1);
    __syncthreads();

    // ---- MFMA sweep, split by column-half ch (acc stays 32 f32) ----
    #pragma unroll
    for (int ch = 0; ch < 2; ++ch) {
        f32x4 acc[4][2];
        #pragma unroll
        for (int rr = 0; rr < 4; ++rr)
            #pragma unroll
            for (int oh = 0; oh < 2; ++oh)
                #pragma unroll
                for (int e = 0; e < 4; ++e) acc[rr][oh][e] = 0.f;

        // A-frags deduped: padded row 4w+dr serves all (rr,ky) with rr+ky==dr
        #pragma unroll
        for (int dr = 0; dr < 6; ++dr) {
            Frag A[3];
            const uint32_t* ap = Xs + (4 * q) * PL + (4 * w + dr) * RS + 2 + 16 * ch + n16;
            #pragma unroll
            for (int kx = 0; kx < 3; ++kx)
                #pragma unroll
                for (int p = 0; p < 4; ++p)
                    A[kx].u[p] = ap[p * PL + kx];
            #pragma unroll
            for (int ky = 0; ky < 3; ++ky) {
                const int rr = dr - ky;
                if (rr >= 0 && rr < 4) {
                    #pragma unroll
                    for (int kx = 0; kx < 3; ++kx) {
                        acc[rr][0] = __builtin_amdgcn_mfma_f32_16x16x32_bf16(
                                         A[kx].v, Bf[ky * 3 + kx][0].v, acc[rr][0], 0, 0, 0);
                        acc[rr][1] = __builtin_amdgcn_mfma_f32_16x16x32_bf16(
                                         A[kx].v, Bf[ky * 3 + kx][1].v, acc[rr][1], 0, 0, 0);
                    }
                }
            }
        }

        // ---- epilogue for this ch: D[m=px 4q+e][n=oc n16], nt stores ----
        #pragma unroll
        for (int oh = 0; oh < 2; ++oh) {
            const int oc = oh * 16 + n16;
            const float bv = oh ? bv1 : bv0;
            #pragma unroll
            for (int rr = 0; rr < 4; ++rr) {
                f32x4 v;
                v[0] = acc[rr][oh][0] + bv;
                v[1] = acc[rr][oh][1] + bv;
                v[2] = acc[rr][oh][2] + bv;
                v[3] = acc[rr][oh][3] + bv;
                float* dst = &out[((size_t)(b * C + oc) * P + (y0 + 4 * w + rr)) * P
                                  + x0 + 16 * ch + 4 * q];
                __builtin_nontemporal_store(v, (f32x4*)dst);
            }
        }
    }
}

extern "C" void kernel_launch(void* const* d_in, const int* in_sizes, int n_in,
                              void* d_out, int out_size, void* d_ws, size_t ws_size,
                              hipStream_t stream) {
    const float* x    = (const float*)d_in[0];
    const float* rbuf = (const float*)d_in[1];
    const float* bbuf = (const float*)d_in[2];
    const float* W    = (const float*)d_in[3];
    const float* bias = (const float*)d_in[4];
    float* out = (float*)d_out;

    conv_mfma<<<1024, 256, 0, stream>>>(x, rbuf, bbuf, W, bias, out);
}

// Round 4
// 136.262 us; speedup vs baseline: 1.4147x; 1.2306x over previous
//
#include <hip/hip_runtime.h>
#include <cstdint>

// StreamNet K3 S1 halo conv, bf16 MFMA implicit-GEMM.
// R9: load-queue-depth restructure. Key R6/R7/R8b finding: duration ==
// hbm_bytes / 2.5 TB/s in ALL three rounds -> pinned at a 2.5 TB/s
// effective-BW wall set by outstanding-load depth (Little's law), not by
// DRAM granularity (R8b's 128B rows didn't move it) nor occupancy.
// R8b also doubled write traffic (nontemporal stores defeat L2 half-line
// merging of the ch0/ch1 64B epilogue halves: WRITE 65.5 -> 129 MB).
// R9:
//   * plain float4 epilogue stores (restore L2 write combining).
//   * ALL global loads issued up front per block: W (9xf4) first, then
//     16 interior f4 + halo scalars (~41 VMEM in flight per thread).
//     W pack waits only on W loads; X loads fly under W pack + Bf build.
//   * W gets its own LDS region (no overlay): 60.2 KB total -> 2 blk/CU,
//     __launch_bounds__(256,2) -> 256-VGPR cap, staged payload no-spill.
//   * keeps R8b: 16x32 tiles (128B rows), grid 1024, XCD swizzle
//     (batch i -> XCD i), column-half-split MFMA sweep.
//
// Padded input Xp[b][c][r][cc], r,cc in [0,258):
//   r < 2           -> bbuf[b][c][r][cc]           (bbuf [B][C][2][258])
//   r>=2, cc < 2    -> rbuf[b][c][r-2][cc]         (rbuf [B][C][256][2])
//   r>=2, cc>=2     -> (cc-2 == 255) ? 0 : x[b][c][r-2][cc-2]

constexpr int B  = 8;
constexpr int C  = 32;
constexpr int P  = 256;
constexpr int KB = 2;
constexpr int TH = 16;            // tile rows
constexpr int TW = 32;            // tile cols
constexpr int RS = 36;            // LDS row stride (dwords); padded col pc stored at 2+pc
constexpr int PL = 652;           // plane stride (dwords); %32=12 (A reads 2-way free), %4=0
constexpr int XSZ = 16 * PL;      // X region: 10432 dwords
constexpr int WOFF = XSZ;         // W region: 4608 dwords
constexpr int LDSZ = XSZ + 4608;  // 15040 dwords = 60160 B -> 2 blocks/CU

typedef short bf16x8 __attribute__((ext_vector_type(8)));
typedef float f32x4  __attribute__((ext_vector_type(4)));
union Frag { uint32_t u[4]; bf16x8 v; };

static __device__ __forceinline__ uint32_t pk_bf16(float lo, float hi) {
    uint32_t a  = __builtin_bit_cast(uint32_t, lo);
    uint32_t b2 = __builtin_bit_cast(uint32_t, hi);
    a  += 0x7FFFu + ((a  >> 16) & 1u);
    b2 += 0x7FFFu + ((b2 >> 16) & 1u);
    return (a >> 16) | (b2 & 0xFFFF0000u);
}

struct St {                        // one plane-pair's staged data
    float4 a0, a1, c0, c1;         // interior: lo plane 8 cols, hi plane 8 cols
    float  h0l, h0h, h1l, h1h;     // 2 halo cells x (lo, hi)
};

__global__ __launch_bounds__(256, 2) void conv_mfma(
    const float* __restrict__ x,      // [B][C][P][P]
    const float* __restrict__ rbuf,   // [B][C][P][KB]
    const float* __restrict__ bbuf,   // [B][C][KB][P+KB]
    const float* __restrict__ W,      // [C][C][3][3]
    const float* __restrict__ bias,   // [C]
    float* __restrict__ out)          // [B][C][P][P]
{
    const int tid  = threadIdx.x;
    const int lane = tid & 63;
    const int w    = tid >> 6;        // wave 0..3
    const int q    = lane >> 4;
    const int n16  = lane & 15;

    // XCD swizzle: round-robin dispatch (blk%8 = XCD) -> XCD i gets swz
    // range [128i,128(i+1)) = all tiles of batch i (8.4MB x, in-XCD halos)
    const int swz = (blockIdx.x & 7) * 128 + (blockIdx.x >> 3);
    const int cx = swz & 7, ty = (swz >> 3) & 15, b = swz >> 7;
    const int x0 = cx * TW, y0 = ty * TH;

    __shared__ uint32_t Xs[LDSZ];

    // ---- staging lane geometry ----
    const int srow = lane >> 2;                    // 0..15
    const int scol = (lane & 3) * 8;               // 0,8,16,24 (8 cols/lane)
    const bool zc  = (x0 == P - TW) && ((lane & 3) == 3);   // col 255 lands in a1.w/c1.w

    // halo cells: 100 = top 2x34 (idx 0..67) + left 16x2 (idx 68..99)
    const float* xb = x    + (size_t)b * C * P * P;
    const float* rb = rbuf + (size_t)b * C * P * KB;
    const float* bb = bbuf + (size_t)b * C * KB * (P + KB);
    const float* basep[3] = { xb, rb, bb };
    const int    psz[3]   = { P * P, P * KB, KB * (P + KB) };

    int h_ldso[2], h_ps[2];
    const float* h_bp[2];
    bool h_z[2];
    #pragma unroll
    for (int ci = 0; ci < 2; ++ci) {
        const int c = lane + 64 * ci;
        int prow, pcol;
        if (c < 68) { const int hr = (c >= 34) ? 1 : 0; prow = hr; pcol = c - 34 * hr; }
        else        { const int cc = c - 68; prow = KB + (cc >> 1); pcol = cc & 1; }
        h_ldso[ci] = prow * RS + 2 + pcol;
        const int gr = y0 + prow, gc = x0 + pcol;
        int sel, off; bool z = false;
        if (gr < KB)      { sel = 2; off = gr * (P + KB) + gc; }
        else if (gc < KB) { sel = 1; off = (gr - KB) * KB + gc; }
        else              { sel = 0; off = (gr - KB) * P + (gc - KB); z = (gc == P + KB - 1); }
        h_bp[ci] = basep[sel] + off;
        h_ps[ci] = psz[sel];
        h_z[ci]  = z;
    }
    const bool h1a = lane < 36;                    // cell1 active

    // ---- 1. issue W loads first (their consumer waits only on them) ----
    float4 wv[9];
    {
        const float4* W4 = (const float4*)W;       // 2304 float4
        #pragma unroll
        for (int k = 0; k < 9; ++k) wv[k] = W4[tid + k * 256];
    }

    // ---- 2. issue ALL X loads (4 plane-pairs/wave, ~32 VMEM deep) ----
    St S[4];
    #pragma unroll
    for (int k2 = 0; k2 < 4; ++k2) {
        const int m = 4 * k2 + w;
        const float* pi = xb + (size_t)(2 * m) * (P * P) + (y0 + srow) * P + x0 + scol;
        S[k2].a0 = *(const float4*)pi;
        S[k2].a1 = *(const float4*)(pi + 4);
        S[k2].c0 = *(const float4*)(pi + P * P);
        S[k2].c1 = *(const float4*)(pi + P * P + 4);
        const float* p0 = h_bp[0] + (size_t)(2 * m) * h_ps[0];
        S[k2].h0l = h_z[0] ? 0.f : p0[0];
        S[k2].h0h = h_z[0] ? 0.f : p0[h_ps[0]];
        if (h1a) {
            const float* p1 = h_bp[1] + (size_t)(2 * m) * h_ps[1];
            S[k2].h1l = h_z[1] ? 0.f : p1[0];
            S[k2].h1h = h_z[1] ? 0.f : p1[h_ps[1]];
        }
    }

    // ---- 3. pack W into its LDS region (X loads still in flight) ----
    {
        uint16_t* Wh = (uint16_t*)(Xs + WOFF);
        #pragma unroll
        for (int k = 0; k < 9; ++k) {
            const int f = (tid + k * 256) * 4;
            const float vv[4] = { wv[k].x, wv[k].y, wv[k].z, wv[k].w };
            #pragma unroll
            for (int e = 0; e < 4; ++e) {
                const int flat = f + e;            // (oc*32+ic)*9 + t
                const int t    = flat % 9;
                const int rest = flat / 9;
                const int ic   = rest & 31;
                const int oc   = rest >> 5;
                const uint32_t u = __builtin_bit_cast(uint32_t, vv[e]);
                const uint16_t h = (uint16_t)((u + 0x7FFFu + ((u >> 16) & 1u)) >> 16);
                Wh[(t * 512 + oc * 16 + (ic >> 1)) * 2 + (ic & 1)] = h;
            }
        }
    }
    __syncthreads();              // W region visible

    // ---- 4. B fragments from LDS (X loads still draining) ----
    Frag Bf[9][2];
    #pragma unroll
    for (int t = 0; t < 9; ++t)
        #pragma unroll
        for (int oh = 0; oh < 2; ++oh)
            *(uint4*)Bf[t][oh].u =
                *(const uint4*)&Xs[WOFF + t * 512 + (oh * 16 + n16) * 16 + q * 4];
    const float bv0 = bias[n16];
    const float bv1 = bias[16 + n16];

    // ---- 5. pack + store X tiles ----
    #pragma unroll
    for (int k2 = 0; k2 < 4; ++k2) {
        const int m = 4 * k2 + w;
        float4 a1 = S[k2].a1, c1 = S[k2].c1;
        if (zc) { a1.w = 0.f; c1.w = 0.f; }
        uint4 u0, u1;
        u0.x = pk_bf16(S[k2].a0.x, S[k2].c0.x); u0.y = pk_bf16(S[k2].a0.y, S[k2].c0.y);
        u0.z = pk_bf16(S[k2].a0.z, S[k2].c0.z); u0.w = pk_bf16(S[k2].a0.w, S[k2].c0.w);
        u1.x = pk_bf16(a1.x, c1.x);             u1.y = pk_bf16(a1.y, c1.y);
        u1.z = pk_bf16(a1.z, c1.z);             u1.w = pk_bf16(a1.w, c1.w);
        uint32_t* base = Xs + m * PL + (srow + KB) * RS + 4 + scol;  // 16B aligned
        *(uint4*)base       = u0;
        *(uint4*)(base + 4) = u1;
        Xs[m * PL + h_ldso[0]] = pk_bf16(S[k2].h0l, S[k2].h0h);
        if (h1a) Xs[m * PL + h_ldso[1]] = pk_bf16(S[k2].h1l, S[k2].h1h);
    }
    __syncthreads();

    // ---- 6. MFMA sweep, split by column-half ch (acc stays 32 f32) ----
    #pragma unroll
    for (int ch = 0; ch < 2; ++ch) {
        f32x4 acc[4][2];
        #pragma unroll
        for (int rr = 0; rr < 4; ++rr)
            #pragma unroll
            for (int oh = 0; oh < 2; ++oh)
                #pragma unroll
                for (int e = 0; e < 4; ++e) acc[rr][oh][e] = 0.f;

        // A-frags deduped: padded row 4w+dr serves all (rr,ky) with rr+ky==dr
        #pragma unroll
        for (int dr = 0; dr < 6; ++dr) {
            Frag A[3];
            const uint32_t* ap = Xs + (4 * q) * PL + (4 * w + dr) * RS + 2 + 16 * ch + n16;
            #pragma unroll
            for (int kx = 0; kx < 3; ++kx)
                #pragma unroll
                for (int p = 0; p < 4; ++p)
                    A[kx].u[p] = ap[p * PL + kx];
            #pragma unroll
            for (int ky = 0; ky < 3; ++ky) {
                const int rr = dr - ky;
                if (rr >= 0 && rr < 4) {
                    #pragma unroll
                    for (int kx = 0; kx < 3; ++kx) {
                        acc[rr][0] = __builtin_amdgcn_mfma_f32_16x16x32_bf16(
                                         A[kx].v, Bf[ky * 3 + kx][0].v, acc[rr][0], 0, 0, 0);
                        acc[rr][1] = __builtin_amdgcn_mfma_f32_16x16x32_bf16(
                                         A[kx].v, Bf[ky * 3 + kx][1].v, acc[rr][1], 0, 0, 0);
                    }
                }
            }
        }

        // ---- epilogue for this ch: plain float4 stores (L2 merges halves) ----
        #pragma unroll
        for (int oh = 0; oh < 2; ++oh) {
            const int oc = oh * 16 + n16;
            const float bv = oh ? bv1 : bv0;
            #pragma unroll
            for (int rr = 0; rr < 4; ++rr) {
                float4 v;
                v.x = acc[rr][oh][0] + bv;
                v.y = acc[rr][oh][1] + bv;
                v.z = acc[rr][oh][2] + bv;
                v.w = acc[rr][oh][3] + bv;
                *(float4*)&out[((size_t)(b * C + oc) * P + (y0 + 4 * w + rr)) * P
                               + x0 + 16 * ch + 4 * q] = v;
            }
        }
    }
}

extern "C" void kernel_launch(void* const* d_in, const int* in_sizes, int n_in,
                              void* d_out, int out_size, void* d_ws, size_t ws_size,
                              hipStream_t stream) {
    const float* x    = (const float*)d_in[0];
    const float* rbuf = (const float*)d_in[1];
    const float* bbuf = (const float*)d_in[2];
    const float* W    = (const float*)d_in[3];
    const float* bias = (const float*)d_in[4];
    float* out = (float*)d_out;

    conv_mfma<<<1024, 256, 0, stream>>>(x, rbuf, bbuf, W, bias, out);
}